// Round 10
// baseline (16176.682 us; speedup 1.0000x reference)
//
#include <hip/hip_runtime.h>
#include <hip/hip_fp16.h>

// LSTM B=64,T=1024,I=256,H=512 — XCD-LOCAL persistent LSTM.
//
// Batch rows are independent: group g = rows [16g,16g+16) lives entirely on
// XCD g (g<4). Team = 32 WGs x 256thr on that XCD; wave owns 4 h-cols x 16
// rows (MFMA 16x16x32, weights [768,16] f16 in regs). h exchanged through the
// XCD's own L2: plain stores (write-through) + sc0 loads (L1-bypass, read L2)
// with per-dword generation tags (t%15)+1 in the f16 LSBs. Packets are
// self-announcing: visible packets imply the producer finished its reads, so
// a 2-slot team buffer is race-free (teammate skew <=1 by gating).
//
// Insurance (all off the fast critical path):
//  - every step each wave also stores its packets to a MALL mirror (sc1) —
//    consumers valve to the mirror after 48 failed L2 attempts (if sc0
//    semantics were wrong we degrade to MALL speed instead of hanging);
//    mirror (4 slots) guarded by a cached own-team 32-flag min check.
//  - claim phase: WGs claim team slots via XCC_ID + agent atomics; if any of
//    XCDs 0-3 got <32 WGs, ALL WGs fall back to the round-9 global-MALL
//    protocol (proven pass, 7.4ms) with blockIdx identity.
//  - fast & fallback compute bit-identical h (same frag mapping, same tags).

#define T_STEPS 1024
#define BATCH   64
#define ISZ     256
#define HSZ     512
#define NWG     256
#define NTHR    256

// ws layout (u64 units unless noted)
#define TB_U64   16384              // teambuf [4][2][2048]
#define MIR_OFF  16384              // mirror  [4][4][2048]; global-mode hbuf4 (3*8192) overlays
#define MIR_U64  32768
#define CTR_BYTE ((TB_U64 + MIR_U64) * 8)    // 393216
#define GFL_BYTE (CTR_BYTE + 64)             // 393280
#define WS_BYTES (GFL_BYTE + 2048)           // 395328

#define TAGMASK 0x0003000300030003ULL
#define VALVE_ATT 48

typedef _Float16 half8  __attribute__((ext_vector_type(8)));
typedef _Float16 half4  __attribute__((ext_vector_type(4)));
typedef float    floatx4 __attribute__((ext_vector_type(4)));
typedef unsigned long long u64;

#define LD_AGENT(p)     __hip_atomic_load((p), __ATOMIC_RELAXED, __HIP_MEMORY_SCOPE_AGENT)
#define ST_AGENT(p, v)  __hip_atomic_store((p), (v), __ATOMIC_RELAXED, __HIP_MEMORY_SCOPE_AGENT)

__device__ __forceinline__ float fast_sigmoid(float x) {
    return 1.0f / (1.0f + __expf(-x));
}
__device__ __forceinline__ float fast_tanh(float x) {
    return 1.0f - 2.0f / (__expf(2.0f * x) + 1.0f);
}
// v in 1..15 -> full 4-bit tag embedded in EACH dword (2 LSBs of each f16)
__device__ __forceinline__ u64 tagbits(int v) {
    u64 d = (u64)(v & 3) | ((u64)((v >> 2) & 3) << 16);
    return d | (d << 32);
}

__global__ __launch_bounds__(NTHR, 1) void lstm_persist(
    const float* __restrict__ x,
    const float* __restrict__ Wf, const float* __restrict__ bfv,
    const float* __restrict__ Wi, const float* __restrict__ biv,
    const float* __restrict__ Wc, const float* __restrict__ bcv,
    const float* __restrict__ Wo, const float* __restrict__ bov,
    u64* __restrict__ wsu, unsigned* __restrict__ ctrs,
    unsigned* __restrict__ gflags)
{
    const int tid  = threadIdx.x;
    const int bid  = blockIdx.x;
    const int w    = tid >> 6;
    const int l    = tid & 63;
    const int lj   = l & 15;
    const int lk   = l >> 4;
    const int gate = lj >> 2;
    const int jc   = lj & 3;

    // ---------------- claim phase ----------------
    __shared__ unsigned sh3[3];
    if (tid == 0) {
        unsigned xcd;
        asm volatile("s_getreg_b32 %0, hwreg(HW_REG_XCC_ID)" : "=s"(xcd));
        xcd &= 7u;
        unsigned slot = __hip_atomic_fetch_add(&ctrs[xcd], 1u, __ATOMIC_RELAXED,
                                               __HIP_MEMORY_SCOPE_AGENT);
        __hip_atomic_fetch_add(&ctrs[8], 1u, __ATOMIC_RELAXED,
                               __HIP_MEMORY_SCOPE_AGENT);
        while (LD_AGENT(&ctrs[8]) < (unsigned)NWG) __builtin_amdgcn_s_sleep(2);
        unsigned fast = 1u;
        for (int xx = 0; xx < 4; ++xx)
            if (LD_AGENT(&ctrs[xx]) < 32u) fast = 2u;
        ST_AGENT(&ctrs[9], fast);     // mode for out_proj (identical racing writes)
        sh3[0] = xcd; sh3[1] = slot; sh3[2] = fast;
    }
    __syncthreads();
    const unsigned xcd  = sh3[0];
    const unsigned slot = sh3[1];
    const bool fastm    = (sh3[2] == 1u);

    u64* teambuf = wsu;                 // [4][2][2048]
    u64* mirror  = wsu + MIR_OFF;       // [4][4][2048]

    if (fastm) {
        // ================= FAST: XCD-local =================
        if (xcd >= 4 || slot >= 32) return;
        const int group = (int)xcd;           // rows [16*group, 16*group+16)
        const int q     = (int)slot * 4 + w;  // col-block 0..127 (h-cols 4q..4q+3)
        const int hc    = q * 4 + jc;

        __shared__ _Float16 hlds[2][16][528];
        __shared__ _Float16 xlds[2][16][264];

        const float* Wg = (gate == 0) ? Wf : (gate == 1) ? Wi : (gate == 2) ? Wc : Wo;
        const float* bg = (gate == 0) ? bfv : (gate == 1) ? biv : (gate == 2) ? bcv : bov;

        half8 Bfrag[24];
        #pragma unroll
        for (int kf = 0; kf < 24; ++kf) {
            half8 v;
            #pragma unroll
            for (int e = 0; e < 8; ++e) {
                int k = (kf << 5) + (lk << 3) + e;
                v[e] = (_Float16)Wg[(size_t)k * HSZ + hc];
            }
            Bfrag[kf] = v;
        }
        const float bias = bg[hc];
        float cst[4] = {0.f, 0.f, 0.f, 0.f};

        const size_t xstr = (size_t)T_STEPS * ISZ;
        const float* xg = x + (size_t)(group * 16) * xstr;

        // prologue: stage x_0 -> xlds[0]
        {
            #pragma unroll
            for (int j = 0; j < 4; ++j) {
                int R = (tid >> 6) + j * 4, i = (tid & 63) * 4;
                floatx4 v = *(const floatx4*)(xg + (size_t)R * xstr + i);
                half4 h4; h4[0]=(_Float16)v[0]; h4[1]=(_Float16)v[1];
                h4[2]=(_Float16)v[2]; h4[3]=(_Float16)v[3];
                union { half4 h; u64 u; } pk; pk.h = h4;
                *(u64*)&xlds[0][R][i] = pk.u;
            }
        }
        __syncthreads();
        floatx4 accx = {0.f, 0.f, 0.f, 0.f};
        #pragma unroll
        for (int kf = 0; kf < 8; ++kf) {
            half8 a = *(const half8*)&xlds[0][lj][kf * 32 + lk * 8];
            accx = __builtin_amdgcn_mfma_f32_16x16x32_f16(a, Bfrag[kf], accx, 0, 0, 0);
        }

        unsigned guard_seen = 0;

        for (int t = 0; t < T_STEPS; ++t) {
            // ---- stage h_{t-1} (L2 sweep, valve to mirror) ----
            if (t > 0) {
                const u64 expp = tagbits(((t - 1) % 15) + 1);
                const u64* l2p = teambuf + ((size_t)group * 2 + ((t - 1) & 1)) * 2048
                                 + (size_t)tid * 8;
                const u64* mrp = mirror + ((size_t)group * 4 + ((t - 1) & 3)) * 2048
                                 + (size_t)tid * 8;
                u64 pk0,pk1,pk2,pk3,pk4,pk5,pk6,pk7;
                int att = 0; bool done = false;
                while (!done) {
                    u64 a0,a1,a2,a3,a4,a5,a6,a7;
                    asm volatile(
                        "global_load_dwordx2 %0, %8, off sc0\n\t"
                        "global_load_dwordx2 %1, %8, off offset:8 sc0\n\t"
                        "global_load_dwordx2 %2, %8, off offset:16 sc0\n\t"
                        "global_load_dwordx2 %3, %8, off offset:24 sc0\n\t"
                        "global_load_dwordx2 %4, %8, off offset:32 sc0\n\t"
                        "global_load_dwordx2 %5, %8, off offset:40 sc0\n\t"
                        "global_load_dwordx2 %6, %8, off offset:48 sc0\n\t"
                        "global_load_dwordx2 %7, %8, off offset:56 sc0\n\t"
                        "s_waitcnt vmcnt(0)"
                        : "=&v"(a0),"=&v"(a1),"=&v"(a2),"=&v"(a3),
                          "=&v"(a4),"=&v"(a5),"=&v"(a6),"=&v"(a7)
                        : "v"(l2p) : "memory");
                    bool ok = ((a0 & TAGMASK) == expp) && ((a1 & TAGMASK) == expp) &&
                              ((a2 & TAGMASK) == expp) && ((a3 & TAGMASK) == expp) &&
                              ((a4 & TAGMASK) == expp) && ((a5 & TAGMASK) == expp) &&
                              ((a6 & TAGMASK) == expp) && ((a7 & TAGMASK) == expp);
                    if (ok) {
                        pk0=a0; pk1=a1; pk2=a2; pk3=a3; pk4=a4; pk5=a5; pk6=a6; pk7=a7;
                        done = true;
                    } else {
                        if (att >= VALVE_ATT) {
                            u64 m0=LD_AGENT(mrp+0), m1=LD_AGENT(mrp+1),
                                m2=LD_AGENT(mrp+2), m3=LD_AGENT(mrp+3),
                                m4=LD_AGENT(mrp+4), m5=LD_AGENT(mrp+5),
                                m6=LD_AGENT(mrp+6), m7=LD_AGENT(mrp+7);
                            bool ok2 = ((m0&TAGMASK)==expp)&&((m1&TAGMASK)==expp)&&
                                       ((m2&TAGMASK)==expp)&&((m3&TAGMASK)==expp)&&
                                       ((m4&TAGMASK)==expp)&&((m5&TAGMASK)==expp)&&
                                       ((m6&TAGMASK)==expp)&&((m7&TAGMASK)==expp);
                            if (ok2) {
                                pk0=m0; pk1=m1; pk2=m2; pk3=m3;
                                pk4=m4; pk5=m5; pk6=m6; pk7=m7;
                                done = true;
                            }
                        }
                        if (!done) __builtin_amdgcn_s_sleep(1);
                    }
                    ++att;
                }
                const int p0 = tid * 8;
                *(u64*)&hlds[t & 1][(p0+0) & 15][((p0+0) >> 4) * 4] = pk0;
                *(u64*)&hlds[t & 1][(p0+1) & 15][((p0+1) >> 4) * 4] = pk1;
                *(u64*)&hlds[t & 1][(p0+2) & 15][((p0+2) >> 4) * 4] = pk2;
                *(u64*)&hlds[t & 1][(p0+3) & 15][((p0+3) >> 4) * 4] = pk3;
                *(u64*)&hlds[t & 1][(p0+4) & 15][((p0+4) >> 4) * 4] = pk4;
                *(u64*)&hlds[t & 1][(p0+5) & 15][((p0+5) >> 4) * 4] = pk5;
                *(u64*)&hlds[t & 1][(p0+6) & 15][((p0+6) >> 4) * 4] = pk6;
                *(u64*)&hlds[t & 1][(p0+7) & 15][((p0+7) >> 4) * 4] = pk7;
            }

            // ---- stage x_{t+1} -> xlds[(t+1)&1] ----
            if (t + 1 < T_STEPS) {
                #pragma unroll
                for (int j = 0; j < 4; ++j) {
                    int R = (tid >> 6) + j * 4, i = (tid & 63) * 4;
                    floatx4 v = *(const floatx4*)(xg + (size_t)R * xstr
                                                  + (size_t)(t + 1) * ISZ + i);
                    half4 h4; h4[0]=(_Float16)v[0]; h4[1]=(_Float16)v[1];
                    h4[2]=(_Float16)v[2]; h4[3]=(_Float16)v[3];
                    union { half4 h; u64 u; } pk; pk.h = h4;
                    *(u64*)&xlds[(t + 1) & 1][R][i] = pk.u;
                }
            }
            __syncthreads();
            if (t > 0 && tid == 0)
                ST_AGENT(&gflags[(int)xcd * 32 + (int)slot], (unsigned)t);

            floatx4 acc0, acc1;
            #pragma unroll
            for (int e = 0; e < 4; ++e) { acc0[e] = accx[e] + bias; acc1[e] = 0.f; }

            if (t > 0) {
                #pragma unroll
                for (int kf = 0; kf < 16; kf += 2) {
                    half8 a0 = *(const half8*)&hlds[t & 1][lj][kf * 32 + lk * 8];
                    half8 a1 = *(const half8*)&hlds[t & 1][lj][(kf + 1) * 32 + lk * 8];
                    acc0 = __builtin_amdgcn_mfma_f32_16x16x32_f16(a0, Bfrag[8 + kf], acc0, 0, 0, 0);
                    acc1 = __builtin_amdgcn_mfma_f32_16x16x32_f16(a1, Bfrag[9 + kf], acc1, 0, 0, 0);
                }
            }

            floatx4 act;
            if (gate == 2) {
                #pragma unroll
                for (int e = 0; e < 4; ++e) act[e] = fast_tanh(acc0[e] + acc1[e]);
            } else {
                #pragma unroll
                for (int e = 0; e < 4; ++e) act[e] = fast_sigmoid(acc0[e] + acc1[e]);
            }

            const int basel = l & ~12;
            float hv[4];
            #pragma unroll
            for (int e = 0; e < 4; ++e) {
                float vf = __shfl(act[e], basel);
                float vi = __shfl(act[e], basel + 4);
                float vc = __shfl(act[e], basel + 8);
                float vo = __shfl(act[e], basel + 12);
                float c  = vf * cst[e] + vi * vc;
                cst[e] = c;
                hv[e] = vo * fast_tanh(c);
            }
            half4 outv;
            #pragma unroll
            for (int col = 0; col < 4; ++col) {
                const int src = ((l & 15) >> 2) * 16 + col;
                float sel = 0.f;
                #pragma unroll
                for (int e = 0; e < 4; ++e) {
                    float tmp = __shfl(hv[e], src);
                    if ((l & 3) == e) sel = tmp;
                }
                outv[col] = (_Float16)sel;
            }

            union { half4 h; u64 u; } pkk; pkk.h = outv;
            pkk.u = (pkk.u & ~TAGMASK) | tagbits((t % 15) + 1);

            if (l < 16)
                *(volatile u64*)(teambuf + ((size_t)group * 2 + (t & 1)) * 2048
                                 + (size_t)q * 16 + l) = pkk.u;

            // mirror guard (cached; own-team 32 flags)
            if (t >= 4 && guard_seen + 3 < (unsigned)t) {
                unsigned f = (l < 32) ? LD_AGENT(&gflags[(int)xcd * 32 + l])
                                      : 0xffffffffu;
                if (__all(f >= (unsigned)(t - 1))) guard_seen = (unsigned)(t - 1);
                else {
                    const unsigned need = (unsigned)(t - 3);
                    while (!__all(f >= need)) {
                        __builtin_amdgcn_s_sleep(1);
                        f = (l < 32) ? LD_AGENT(&gflags[(int)xcd * 32 + l])
                                     : 0xffffffffu;
                    }
                    guard_seen = need;
                }
            }
            if (l < 16)
                ST_AGENT(mirror + ((size_t)group * 4 + (t & 3)) * 2048
                         + (size_t)q * 16 + l, pkk.u);

            if (t + 1 < T_STEPS) {
                floatx4 az = {0.f, 0.f, 0.f, 0.f};
                #pragma unroll
                for (int kf = 0; kf < 8; ++kf) {
                    half8 a = *(const half8*)&xlds[(t + 1) & 1][lj][kf * 32 + lk * 8];
                    az = __builtin_amdgcn_mfma_f32_16x16x32_f16(a, Bfrag[kf], az, 0, 0, 0);
                }
                accx = az;
            }
        }
        return;
    }

    // ================= FALLBACK: round-9 global-MALL protocol =================
    if (bid >= 128) return;
    {
        const int g    = bid;
        const int row0 = w << 4;
        const int arow = row0 + lj;
        const int pidx = (g << 2) + w;
        u64* hbuf4 = mirror;                        // 3*8192 u64 fits in mirror region
        unsigned* pflags = gflags;                  // 512 u32

        const float* Wg = (gate == 0) ? Wf : (gate == 1) ? Wi : (gate == 2) ? Wc : Wo;
        const float* bg = (gate == 0) ? bfv : (gate == 1) ? biv : (gate == 2) ? bcv : bov;

        half8 Bfrag[24];
        #pragma unroll
        for (int kf = 0; kf < 24; ++kf) {
            half8 v;
            #pragma unroll
            for (int e = 0; e < 8; ++e) {
                int k = (kf << 5) + (lk << 3) + e;
                v[e] = (_Float16)Wg[(size_t)k * HSZ + ((g << 2) + jc)];
            }
            Bfrag[kf] = v;
        }
        const float bias = bg[(g << 2) + jc];
        float cst[4] = {0.f, 0.f, 0.f, 0.f};
        const u64* pfl = (const u64*)pflags;

        floatx4 accx = {0.f, 0.f, 0.f, 0.f};
        {
            const float* xr = x + (size_t)arow * T_STEPS * ISZ + (lk << 3);
            #pragma unroll
            for (int kf = 0; kf < 8; ++kf) {
                floatx4 x0 = *(const floatx4*)(xr + (kf << 5));
                floatx4 x1 = *(const floatx4*)(xr + (kf << 5) + 4);
                half8 a;
                a[0]=(_Float16)x0[0]; a[1]=(_Float16)x0[1]; a[2]=(_Float16)x0[2]; a[3]=(_Float16)x0[3];
                a[4]=(_Float16)x1[0]; a[5]=(_Float16)x1[1]; a[6]=(_Float16)x1[2]; a[7]=(_Float16)x1[3];
                accx = __builtin_amdgcn_mfma_f32_16x16x32_f16(a, Bfrag[kf], accx, 0, 0, 0);
            }
        }
        unsigned minP_seen = 0;
        for (int t = 0; t < T_STEPS; ++t) {
            u64 hl[32];
            u64 pv[4] = {0, 0, 0, 0};
            const bool need_guard = (t >= 3) && (minP_seen < (unsigned)(t - 2));
            if (t > 0) {
                const u64 expp = tagbits(((t - 1) % 15) + 1);
                const u64* hr = hbuf4 + (size_t)(t % 3) * 8192 + arow;
                for (;;) {
                    #pragma unroll
                    for (int kf = 0; kf < 16; ++kf) {
                        const int c0 = kf * 8 + lk * 2;
                        hl[2 * kf]     = LD_AGENT(hr + (size_t)c0 * BATCH);
                        hl[2 * kf + 1] = LD_AGENT(hr + (size_t)(c0 + 1) * BATCH);
                    }
                    bool ok = true;
                    #pragma unroll
                    for (int i = 0; i < 32; ++i) ok &= ((hl[i] & TAGMASK) == expp);
                    if (__all(ok)) break;
                    __builtin_amdgcn_s_sleep(1);
                }
                if (l == 0) ST_AGENT(&pflags[pidx], (unsigned)t);
                if (need_guard) {
                    #pragma unroll
                    for (int j = 0; j < 4; ++j) pv[j] = LD_AGENT(pfl + l + (j << 6));
                }
            }
            floatx4 acc0, acc1;
            #pragma unroll
            for (int e = 0; e < 4; ++e) { acc0[e] = accx[e] + bias; acc1[e] = 0.f; }
            if (t > 0) {
                #pragma unroll
                for (int kf = 0; kf < 16; kf += 2) {
                    union { u64 u[2]; half8 h; } a0, a1;
                    a0.u[0] = hl[2*kf];   a0.u[1] = hl[2*kf+1];
                    a1.u[0] = hl[2*kf+2]; a1.u[1] = hl[2*kf+3];
                    acc0 = __builtin_amdgcn_mfma_f32_16x16x32_f16(a0.h, Bfrag[8+kf], acc0, 0, 0, 0);
                    acc1 = __builtin_amdgcn_mfma_f32_16x16x32_f16(a1.h, Bfrag[9+kf], acc1, 0, 0, 0);
                }
            }
            floatx4 act;
            if (gate == 2) {
                #pragma unroll
                for (int e = 0; e < 4; ++e) act[e] = fast_tanh(acc0[e] + acc1[e]);
            } else {
                #pragma unroll
                for (int e = 0; e < 4; ++e) act[e] = fast_sigmoid(acc0[e] + acc1[e]);
            }
            const int basel = l & ~12;
            float hv[4];
            #pragma unroll
            for (int e = 0; e < 4; ++e) {
                float vf = __shfl(act[e], basel);
                float vi = __shfl(act[e], basel + 4);
                float vc = __shfl(act[e], basel + 8);
                float vo = __shfl(act[e], basel + 12);
                float c  = vf * cst[e] + vi * vc;
                cst[e] = c;
                hv[e] = vo * fast_tanh(c);
            }
            half4 outv;
            #pragma unroll
            for (int col = 0; col < 4; ++col) {
                const int src = ((l & 15) >> 2) * 16 + col;
                float sel = 0.f;
                #pragma unroll
                for (int e = 0; e < 4; ++e) {
                    float tmp = __shfl(hv[e], src);
                    if ((l & 3) == e) sel = tmp;
                }
                outv[col] = (_Float16)sel;
            }
            if (need_guard) {
                const unsigned need = (unsigned)(t - 2);
                for (;;) {
                    unsigned m = 0xffffffffu;
                    #pragma unroll
                    for (int j = 0; j < 4; ++j) {
                        unsigned lo = (unsigned)pv[j], hi = (unsigned)(pv[j] >> 32);
                        m = m < lo ? m : lo;
                        m = m < hi ? m : hi;
                    }
                    if (__all(m >= need + 2)) { minP_seen = need + 2; break; }
                    if (__all(m >= need)) break;
                    __builtin_amdgcn_s_sleep(1);
                    #pragma unroll
                    for (int j = 0; j < 4; ++j) pv[j] = LD_AGENT(pfl + l + (j << 6));
                }
            }
            u64* hw = hbuf4 + (size_t)((t + 1) % 3) * 8192 + (size_t)g * BATCH + row0;
            if (l < 16) {
                union { half4 h; u64 u; } pk; pk.h = outv;
                pk.u = (pk.u & ~TAGMASK) | tagbits((t % 15) + 1);
                ST_AGENT(hw + l, pk.u);
            }
            if (t + 1 < T_STEPS) {
                floatx4 az = {0.f, 0.f, 0.f, 0.f};
                const float* xr = x + ((size_t)arow * T_STEPS + (t + 1)) * ISZ + (lk << 3);
                #pragma unroll
                for (int kf = 0; kf < 8; ++kf) {
                    floatx4 x0 = *(const floatx4*)(xr + (kf << 5));
                    floatx4 x1 = *(const floatx4*)(xr + (kf << 5) + 4);
                    half8 a;
                    a[0]=(_Float16)x0[0]; a[1]=(_Float16)x0[1]; a[2]=(_Float16)x0[2]; a[3]=(_Float16)x0[3];
                    a[4]=(_Float16)x1[0]; a[5]=(_Float16)x1[1]; a[6]=(_Float16)x1[2]; a[7]=(_Float16)x1[3];
                    az = __builtin_amdgcn_mfma_f32_16x16x32_f16(a, Bfrag[kf], az, 0, 0, 0);
                }
                accx = az;
            }
        }
    }
}

__global__ void out_proj(const u64* __restrict__ wsu, const unsigned* __restrict__ ctrs,
                         const float* __restrict__ Wfc, const float* __restrict__ bfc,
                         float* __restrict__ out)
{
    const int b = blockIdx.x;      // 64
    const int l = threadIdx.x;     // 64
    const bool fastm = (ctrs[9] == 1u);
    float s = 0.f;
    if (fastm) {
        const int grp = b >> 4, r = b & 15;
        const u64* mb = wsu + MIR_OFF + ((size_t)grp * 4 + 3) * 2048;  // gen 1023 slot 3
        #pragma unroll
        for (int j = 0; j < 2; ++j) {
            const int q = l + (j << 6);
            union { u64 u; half4 h; } v;
            v.u = mb[(size_t)q * 16 + r];
            #pragma unroll
            for (int e = 0; e < 4; ++e) s += (float)v.h[e] * Wfc[q * 4 + e];
        }
    } else {
        const u64* hb4 = wsu + MIR_OFF + (size_t)(T_STEPS % 3) * 8192;  // slot 1
        #pragma unroll
        for (int j = 0; j < 2; ++j) {
            const int c4 = l + (j << 6);
            union { u64 u; half4 h; } v;
            v.u = hb4[(size_t)c4 * BATCH + b];
            #pragma unroll
            for (int e = 0; e < 4; ++e) s += (float)v.h[e] * Wfc[c4 * 4 + e];
        }
    }
    #pragma unroll
    for (int off = 32; off; off >>= 1) s += __shfl_down(s, off);
    if (l == 0) out[b] = s + bfc[0];
}

extern "C" void kernel_launch(void* const* d_in, const int* in_sizes, int n_in,
                              void* d_out, int out_size, void* d_ws, size_t ws_size,
                              hipStream_t stream)
{
    const float* x   = (const float*)d_in[0];
    const float* Wf  = (const float*)d_in[1];
    const float* bf  = (const float*)d_in[2];
    const float* Wi  = (const float*)d_in[3];
    const float* bi  = (const float*)d_in[4];
    const float* Wc  = (const float*)d_in[5];
    const float* bc  = (const float*)d_in[6];
    const float* Wo  = (const float*)d_in[7];
    const float* bo  = (const float*)d_in[8];
    const float* Wfc = (const float*)d_in[9];
    const float* bfc = (const float*)d_in[10];

    u64* wsu = (u64*)d_ws;
    unsigned* ctrs   = (unsigned*)((char*)d_ws + CTR_BYTE);
    unsigned* gflags = (unsigned*)((char*)d_ws + GFL_BYTE);

    // zero team buffers, mirror, counters, flags every launch (tags 1..15;
    // zeros/poison decode as tag 0 -> never accepted)
    (void)hipMemsetAsync(d_ws, 0, WS_BYTES, stream);

    lstm_persist<<<dim3(NWG), dim3(NTHR), 0, stream>>>(
        x, Wf, bf, Wi, bi, Wc, bc, Wo, bo, wsu, ctrs, gflags);

    out_proj<<<dim3(BATCH), dim3(64), 0, stream>>>(wsu, ctrs, Wfc, bfc, (float*)d_out);
}

// Round 11
// 7249.427 us; speedup vs baseline: 2.2314x; 2.2314x over previous
//
#include <hip/hip_runtime.h>
#include <hip/hip_fp16.h>

// LSTM B=64,T=1024,I=256,H=512 — XCD-LOCAL persistent LSTM, round 11.
//
// Teams: group g = batch rows [16g,16g+16) on XCD g (g<4); 32 WGs/team; wave
// owns 4 h-cols (q=slot*4+w). Weights [768,16] f16 in regs. h exchanged via
// the XCD's own L2 with EXPLICIT sc0 pairing on both sides:
//   producer: asm global_store_dwordx2 ... sc0   (coherent at L2)
//   consumer: asm global_load_dwordx2  ... sc0   (L1 bypass, read L2)
// Packets carry per-dword generation tags (t%15)+1 in the f16 LSBs; the
// sweep IS the poll. Full-panel sweep bounds team skew <=1 => 2 teambuf
// slots and 4 mirror slots are overwrite-safe WITHOUT any flags/guards
// (deleted this round; round-10's guard was both unnecessary and executed
// every step, costing a MALL RT).
//
// Insurance: producers also ST_AGENT each packet to a MALL mirror (4 slots);
// consumers valve to LD_AGENT mirror reads after 16 failed L2 attempts.
// Round 10 passed running (we believe) entirely on this path at 16us/step,
// so worst case repeats ~that minus guard; best case L2 sweeps succeed and
// the step collapses to ~1.5-2us.
//
// Claim phase: WGs claim team slots via XCC_ID + agent atomics; imperfect
// claim => ALL WGs run the round-9 global-MALL fallback (proven pass).

#define T_STEPS 1024
#define BATCH   64
#define ISZ     256
#define HSZ     512
#define NWG     256
#define NTHR    256

// ws layout (u64 units unless noted)
#define TB_U64   16384              // teambuf [4][2][2048]
#define MIR_OFF  16384              // mirror  [4][4][2048]; fallback hbuf overlays
#define MIR_U64  32768
#define CTR_BYTE ((TB_U64 + MIR_U64) * 8)    // 393216
#define GFL_BYTE (CTR_BYTE + 64)             // 393280
#define WS_BYTES (GFL_BYTE + 2048)           // 395328

#define TAGMASK 0x0003000300030003ULL
#define VALVE_ATT 16

typedef _Float16 half8  __attribute__((ext_vector_type(8)));
typedef _Float16 half4  __attribute__((ext_vector_type(4)));
typedef float    floatx4 __attribute__((ext_vector_type(4)));
typedef unsigned long long u64;

#define LD_AGENT(p)     __hip_atomic_load((p), __ATOMIC_RELAXED, __HIP_MEMORY_SCOPE_AGENT)
#define ST_AGENT(p, v)  __hip_atomic_store((p), (v), __ATOMIC_RELAXED, __HIP_MEMORY_SCOPE_AGENT)

__device__ __forceinline__ float fast_sigmoid(float x) {
    return 1.0f / (1.0f + __expf(-x));
}
__device__ __forceinline__ float fast_tanh(float x) {
    return 1.0f - 2.0f / (__expf(2.0f * x) + 1.0f);
}
// v in 1..15 -> full 4-bit tag embedded in EACH dword (2 LSBs of each f16)
__device__ __forceinline__ u64 tagbits(int v) {
    u64 d = (u64)(v & 3) | ((u64)((v >> 2) & 3) << 16);
    return d | (d << 32);
}

__global__ __launch_bounds__(NTHR, 1) void lstm_persist(
    const float* __restrict__ x,
    const float* __restrict__ Wf, const float* __restrict__ bfv,
    const float* __restrict__ Wi, const float* __restrict__ biv,
    const float* __restrict__ Wc, const float* __restrict__ bcv,
    const float* __restrict__ Wo, const float* __restrict__ bov,
    u64* __restrict__ wsu, unsigned* __restrict__ ctrs,
    unsigned* __restrict__ gflags)
{
    const int tid  = threadIdx.x;
    const int bid  = blockIdx.x;
    const int w    = tid >> 6;
    const int l    = tid & 63;
    const int lj   = l & 15;
    const int lk   = l >> 4;
    const int gate = lj >> 2;
    const int jc   = lj & 3;

    // ---------------- claim phase ----------------
    __shared__ unsigned sh3[3];
    if (tid == 0) {
        unsigned xcd;
        asm volatile("s_getreg_b32 %0, hwreg(HW_REG_XCC_ID)" : "=s"(xcd));
        xcd &= 7u;
        unsigned slot = __hip_atomic_fetch_add(&ctrs[xcd], 1u, __ATOMIC_RELAXED,
                                               __HIP_MEMORY_SCOPE_AGENT);
        __hip_atomic_fetch_add(&ctrs[8], 1u, __ATOMIC_RELAXED,
                               __HIP_MEMORY_SCOPE_AGENT);
        while (LD_AGENT(&ctrs[8]) < (unsigned)NWG) __builtin_amdgcn_s_sleep(2);
        unsigned fast = 1u;
        for (int xx = 0; xx < 4; ++xx)
            if (LD_AGENT(&ctrs[xx]) < 32u) fast = 2u;
        ST_AGENT(&ctrs[9], fast);     // mode for out_proj (identical racing writes)
        sh3[0] = xcd; sh3[1] = slot; sh3[2] = fast;
    }
    __syncthreads();
    const unsigned xcd  = sh3[0];
    const unsigned slot = sh3[1];
    const bool fastm    = (sh3[2] == 1u);

    u64* teambuf = wsu;                 // [4][2][2048]
    u64* mirror  = wsu + MIR_OFF;       // [4][4][2048]

    if (fastm) {
        // ================= FAST: XCD-local =================
        if (xcd >= 4 || slot >= 32) return;
        const int group = (int)xcd;           // rows [16*group, 16*group+16)
        const int q     = (int)slot * 4 + w;  // col-block 0..127
        const int hc    = q * 4 + jc;

        __shared__ _Float16 hlds[2][16][520];   // 520: 2-way LDS conflict only
        __shared__ _Float16 xlds[2][16][264];

        const float* Wg = (gate == 0) ? Wf : (gate == 1) ? Wi : (gate == 2) ? Wc : Wo;
        const float* bg = (gate == 0) ? bfv : (gate == 1) ? biv : (gate == 2) ? bcv : bov;

        half8 Bfrag[24];
        #pragma unroll
        for (int kf = 0; kf < 24; ++kf) {
            half8 v;
            #pragma unroll
            for (int e = 0; e < 8; ++e) {
                int k = (kf << 5) + (lk << 3) + e;
                v[e] = (_Float16)Wg[(size_t)k * HSZ + hc];
            }
            Bfrag[kf] = v;
        }
        const float bias = bg[hc];
        float cst[4] = {0.f, 0.f, 0.f, 0.f};

        const size_t xstr = (size_t)T_STEPS * ISZ;
        const float* xg = x + (size_t)(group * 16) * xstr;

        // prologue: stage x_0 -> xlds[0]
        #pragma unroll
        for (int j = 0; j < 4; ++j) {
            int R = (tid >> 6) + j * 4, i = (tid & 63) * 4;
            floatx4 v = *(const floatx4*)(xg + (size_t)R * xstr + i);
            half4 h4; h4[0]=(_Float16)v[0]; h4[1]=(_Float16)v[1];
            h4[2]=(_Float16)v[2]; h4[3]=(_Float16)v[3];
            union { half4 h; u64 u; } pk; pk.h = h4;
            *(u64*)&xlds[0][R][i] = pk.u;
        }
        __syncthreads();
        floatx4 accx = {0.f, 0.f, 0.f, 0.f};
        #pragma unroll
        for (int kf = 0; kf < 8; ++kf) {
            half8 a = *(const half8*)&xlds[0][lj][kf * 32 + lk * 8];
            accx = __builtin_amdgcn_mfma_f32_16x16x32_f16(a, Bfrag[kf], accx, 0, 0, 0);
        }

        for (int t = 0; t < T_STEPS; ++t) {
            // ---- sweep h_{t-1} from team L2 buf (valve to MALL mirror) ----
            if (t > 0) {
                const u64 expp = tagbits(((t - 1) % 15) + 1);
                const u64* l2p = teambuf + ((size_t)group * 2 + ((t - 1) & 1)) * 2048
                                 + (size_t)tid * 8;
                const u64* mrp = mirror + ((size_t)group * 4 + ((t - 1) & 3)) * 2048
                                 + (size_t)tid * 8;
                u64 pk0,pk1,pk2,pk3,pk4,pk5,pk6,pk7;
                int att = 0; bool done = false;
                while (!done) {
                    u64 a0,a1,a2,a3,a4,a5,a6,a7;
                    asm volatile(
                        "global_load_dwordx2 %0, %8, off sc0\n\t"
                        "global_load_dwordx2 %1, %8, off offset:8 sc0\n\t"
                        "global_load_dwordx2 %2, %8, off offset:16 sc0\n\t"
                        "global_load_dwordx2 %3, %8, off offset:24 sc0\n\t"
                        "global_load_dwordx2 %4, %8, off offset:32 sc0\n\t"
                        "global_load_dwordx2 %5, %8, off offset:40 sc0\n\t"
                        "global_load_dwordx2 %6, %8, off offset:48 sc0\n\t"
                        "global_load_dwordx2 %7, %8, off offset:56 sc0\n\t"
                        "s_waitcnt vmcnt(0)"
                        : "=&v"(a0),"=&v"(a1),"=&v"(a2),"=&v"(a3),
                          "=&v"(a4),"=&v"(a5),"=&v"(a6),"=&v"(a7)
                        : "v"(l2p) : "memory");
                    bool ok = ((a0 & TAGMASK) == expp) && ((a1 & TAGMASK) == expp) &&
                              ((a2 & TAGMASK) == expp) && ((a3 & TAGMASK) == expp) &&
                              ((a4 & TAGMASK) == expp) && ((a5 & TAGMASK) == expp) &&
                              ((a6 & TAGMASK) == expp) && ((a7 & TAGMASK) == expp);
                    if (ok) {
                        pk0=a0; pk1=a1; pk2=a2; pk3=a3; pk4=a4; pk5=a5; pk6=a6; pk7=a7;
                        done = true;
                    } else {
                        if (att >= VALVE_ATT) {
                            u64 m0=LD_AGENT(mrp+0), m1=LD_AGENT(mrp+1),
                                m2=LD_AGENT(mrp+2), m3=LD_AGENT(mrp+3),
                                m4=LD_AGENT(mrp+4), m5=LD_AGENT(mrp+5),
                                m6=LD_AGENT(mrp+6), m7=LD_AGENT(mrp+7);
                            bool ok2 = ((m0&TAGMASK)==expp)&&((m1&TAGMASK)==expp)&&
                                       ((m2&TAGMASK)==expp)&&((m3&TAGMASK)==expp)&&
                                       ((m4&TAGMASK)==expp)&&((m5&TAGMASK)==expp)&&
                                       ((m6&TAGMASK)==expp)&&((m7&TAGMASK)==expp);
                            if (ok2) {
                                pk0=m0; pk1=m1; pk2=m2; pk3=m3;
                                pk4=m4; pk5=m5; pk6=m6; pk7=m7;
                                done = true;
                            }
                        }
                        if (!done) __builtin_amdgcn_s_sleep(1);
                    }
                    ++att;
                }
                const int p0 = tid * 8;
                *(u64*)&hlds[t & 1][(p0+0) & 15][((p0+0) >> 4) * 4] = pk0;
                *(u64*)&hlds[t & 1][(p0+1) & 15][((p0+1) >> 4) * 4] = pk1;
                *(u64*)&hlds[t & 1][(p0+2) & 15][((p0+2) >> 4) * 4] = pk2;
                *(u64*)&hlds[t & 1][(p0+3) & 15][((p0+3) >> 4) * 4] = pk3;
                *(u64*)&hlds[t & 1][(p0+4) & 15][((p0+4) >> 4) * 4] = pk4;
                *(u64*)&hlds[t & 1][(p0+5) & 15][((p0+5) >> 4) * 4] = pk5;
                *(u64*)&hlds[t & 1][(p0+6) & 15][((p0+6) >> 4) * 4] = pk6;
                *(u64*)&hlds[t & 1][(p0+7) & 15][((p0+7) >> 4) * 4] = pk7;
            }

            // ---- stage x_{t+1} -> xlds[(t+1)&1] ----
            if (t + 1 < T_STEPS) {
                #pragma unroll
                for (int j = 0; j < 4; ++j) {
                    int R = (tid >> 6) + j * 4, i = (tid & 63) * 4;
                    floatx4 v = *(const floatx4*)(xg + (size_t)R * xstr
                                                  + (size_t)(t + 1) * ISZ + i);
                    half4 h4; h4[0]=(_Float16)v[0]; h4[1]=(_Float16)v[1];
                    h4[2]=(_Float16)v[2]; h4[3]=(_Float16)v[3];
                    union { half4 h; u64 u; } pk; pk.h = h4;
                    *(u64*)&xlds[(t + 1) & 1][R][i] = pk.u;
                }
            }
            __syncthreads();

            floatx4 acc0, acc1;
            #pragma unroll
            for (int e = 0; e < 4; ++e) { acc0[e] = accx[e] + bias; acc1[e] = 0.f; }

            if (t > 0) {
                #pragma unroll
                for (int kf = 0; kf < 16; kf += 2) {
                    half8 a0 = *(const half8*)&hlds[t & 1][lj][kf * 32 + lk * 8];
                    half8 a1 = *(const half8*)&hlds[t & 1][lj][(kf + 1) * 32 + lk * 8];
                    acc0 = __builtin_amdgcn_mfma_f32_16x16x32_f16(a0, Bfrag[8 + kf], acc0, 0, 0, 0);
                    acc1 = __builtin_amdgcn_mfma_f32_16x16x32_f16(a1, Bfrag[9 + kf], acc1, 0, 0, 0);
                }
            }

            floatx4 act;
            if (gate == 2) {
                #pragma unroll
                for (int e = 0; e < 4; ++e) act[e] = fast_tanh(acc0[e] + acc1[e]);
            } else {
                #pragma unroll
                for (int e = 0; e < 4; ++e) act[e] = fast_sigmoid(acc0[e] + acc1[e]);
            }

            const int basel = l & ~12;
            float hv[4];
            #pragma unroll
            for (int e = 0; e < 4; ++e) {
                float vf = __shfl(act[e], basel);
                float vi = __shfl(act[e], basel + 4);
                float vc = __shfl(act[e], basel + 8);
                float vo = __shfl(act[e], basel + 12);
                float c  = vf * cst[e] + vi * vc;
                cst[e] = c;
                hv[e] = vo * fast_tanh(c);
            }
            half4 outv;
            #pragma unroll
            for (int col = 0; col < 4; ++col) {
                const int src = ((l & 15) >> 2) * 16 + col;
                float sel = 0.f;
                #pragma unroll
                for (int e = 0; e < 4; ++e) {
                    float tmp = __shfl(hv[e], src);
                    if ((l & 3) == e) sel = tmp;
                }
                outv[col] = (_Float16)sel;
            }

            union { half4 h; u64 u; } pkk; pkk.h = outv;
            pkk.u = (pkk.u & ~TAGMASK) | tagbits((t % 15) + 1);

            if (l < 16) {
                // teambuf store with explicit sc0 (coherent at this XCD's L2)
                u64* tp = teambuf + ((size_t)group * 2 + (t & 1)) * 2048
                          + (size_t)q * 16 + l;
                asm volatile("global_store_dwordx2 %0, %1, off sc0"
                             :: "v"(tp), "v"(pkk.u) : "memory");
                // MALL mirror (valve + out_proj path), fire-and-forget
                ST_AGENT(mirror + ((size_t)group * 4 + (t & 3)) * 2048
                         + (size_t)q * 16 + l, pkk.u);
            }

            if (t + 1 < T_STEPS) {
                floatx4 az = {0.f, 0.f, 0.f, 0.f};
                #pragma unroll
                for (int kf = 0; kf < 8; ++kf) {
                    half8 a = *(const half8*)&xlds[(t + 1) & 1][lj][kf * 32 + lk * 8];
                    az = __builtin_amdgcn_mfma_f32_16x16x32_f16(a, Bfrag[kf], az, 0, 0, 0);
                }
                accx = az;
            }
        }
        return;
    }

    // ================= FALLBACK: round-9 global-MALL protocol =================
    if (bid >= 128) return;
    {
        const int g    = bid;
        const int row0 = w << 4;
        const int arow = row0 + lj;
        const int pidx = (g << 2) + w;
        u64* hbuf4 = mirror;                        // 3*8192 u64 fits in mirror region
        unsigned* pflags = gflags;                  // 512 u32

        const float* Wg = (gate == 0) ? Wf : (gate == 1) ? Wi : (gate == 2) ? Wc : Wo;
        const float* bg = (gate == 0) ? bfv : (gate == 1) ? biv : (gate == 2) ? bcv : bov;

        half8 Bfrag[24];
        #pragma unroll
        for (int kf = 0; kf < 24; ++kf) {
            half8 v;
            #pragma unroll
            for (int e = 0; e < 8; ++e) {
                int k = (kf << 5) + (lk << 3) + e;
                v[e] = (_Float16)Wg[(size_t)k * HSZ + ((g << 2) + jc)];
            }
            Bfrag[kf] = v;
        }
        const float bias = bg[(g << 2) + jc];
        float cst[4] = {0.f, 0.f, 0.f, 0.f};
        const u64* pfl = (const u64*)pflags;

        floatx4 accx = {0.f, 0.f, 0.f, 0.f};
        {
            const float* xr = x + (size_t)arow * T_STEPS * ISZ + (lk << 3);
            #pragma unroll
            for (int kf = 0; kf < 8; ++kf) {
                floatx4 x0 = *(const floatx4*)(xr + (kf << 5));
                floatx4 x1 = *(const floatx4*)(xr + (kf << 5) + 4);
                half8 a;
                a[0]=(_Float16)x0[0]; a[1]=(_Float16)x0[1]; a[2]=(_Float16)x0[2]; a[3]=(_Float16)x0[3];
                a[4]=(_Float16)x1[0]; a[5]=(_Float16)x1[1]; a[6]=(_Float16)x1[2]; a[7]=(_Float16)x1[3];
                accx = __builtin_amdgcn_mfma_f32_16x16x32_f16(a, Bfrag[kf], accx, 0, 0, 0);
            }
        }
        unsigned minP_seen = 0;
        for (int t = 0; t < T_STEPS; ++t) {
            u64 hl[32];
            u64 pv[4] = {0, 0, 0, 0};
            const bool need_guard = (t >= 3) && (minP_seen < (unsigned)(t - 2));
            if (t > 0) {
                const u64 expp = tagbits(((t - 1) % 15) + 1);
                const u64* hr = hbuf4 + (size_t)(t % 3) * 8192 + arow;
                for (;;) {
                    #pragma unroll
                    for (int kf = 0; kf < 16; ++kf) {
                        const int c0 = kf * 8 + lk * 2;
                        hl[2 * kf]     = LD_AGENT(hr + (size_t)c0 * BATCH);
                        hl[2 * kf + 1] = LD_AGENT(hr + (size_t)(c0 + 1) * BATCH);
                    }
                    bool ok = true;
                    #pragma unroll
                    for (int i = 0; i < 32; ++i) ok &= ((hl[i] & TAGMASK) == expp);
                    if (__all(ok)) break;
                    __builtin_amdgcn_s_sleep(1);
                }
                if (l == 0) ST_AGENT(&pflags[pidx], (unsigned)t);
                if (need_guard) {
                    #pragma unroll
                    for (int j = 0; j < 4; ++j) pv[j] = LD_AGENT(pfl + l + (j << 6));
                }
            }
            floatx4 acc0, acc1;
            #pragma unroll
            for (int e = 0; e < 4; ++e) { acc0[e] = accx[e] + bias; acc1[e] = 0.f; }
            if (t > 0) {
                #pragma unroll
                for (int kf = 0; kf < 16; kf += 2) {
                    union { u64 u[2]; half8 h; } a0, a1;
                    a0.u[0] = hl[2*kf];   a0.u[1] = hl[2*kf+1];
                    a1.u[0] = hl[2*kf+2]; a1.u[1] = hl[2*kf+3];
                    acc0 = __builtin_amdgcn_mfma_f32_16x16x32_f16(a0.h, Bfrag[8+kf], acc0, 0, 0, 0);
                    acc1 = __builtin_amdgcn_mfma_f32_16x16x32_f16(a1.h, Bfrag[9+kf], acc1, 0, 0, 0);
                }
            }
            floatx4 act;
            if (gate == 2) {
                #pragma unroll
                for (int e = 0; e < 4; ++e) act[e] = fast_tanh(acc0[e] + acc1[e]);
            } else {
                #pragma unroll
                for (int e = 0; e < 4; ++e) act[e] = fast_sigmoid(acc0[e] + acc1[e]);
            }
            const int basel = l & ~12;
            float hv[4];
            #pragma unroll
            for (int e = 0; e < 4; ++e) {
                float vf = __shfl(act[e], basel);
                float vi = __shfl(act[e], basel + 4);
                float vc = __shfl(act[e], basel + 8);
                float vo = __shfl(act[e], basel + 12);
                float c  = vf * cst[e] + vi * vc;
                cst[e] = c;
                hv[e] = vo * fast_tanh(c);
            }
            half4 outv;
            #pragma unroll
            for (int col = 0; col < 4; ++col) {
                const int src = ((l & 15) >> 2) * 16 + col;
                float sel = 0.f;
                #pragma unroll
                for (int e = 0; e < 4; ++e) {
                    float tmp = __shfl(hv[e], src);
                    if ((l & 3) == e) sel = tmp;
                }
                outv[col] = (_Float16)sel;
            }
            if (need_guard) {
                const unsigned need = (unsigned)(t - 2);
                for (;;) {
                    unsigned m = 0xffffffffu;
                    #pragma unroll
                    for (int j = 0; j < 4; ++j) {
                        unsigned lo = (unsigned)pv[j], hi = (unsigned)(pv[j] >> 32);
                        m = m < lo ? m : lo;
                        m = m < hi ? m : hi;
                    }
                    if (__all(m >= need + 2)) { minP_seen = need + 2; break; }
                    if (__all(m >= need)) break;
                    __builtin_amdgcn_s_sleep(1);
                    #pragma unroll
                    for (int j = 0; j < 4; ++j) pv[j] = LD_AGENT(pfl + l + (j << 6));
                }
            }
            u64* hw = hbuf4 + (size_t)((t + 1) % 3) * 8192 + (size_t)g * BATCH + row0;
            if (l < 16) {
                union { half4 h; u64 u; } pk; pk.h = outv;
                pk.u = (pk.u & ~TAGMASK) | tagbits((t % 15) + 1);
                ST_AGENT(hw + l, pk.u);
            }
            if (t + 1 < T_STEPS) {
                floatx4 az = {0.f, 0.f, 0.f, 0.f};
                const float* xr = x + ((size_t)arow * T_STEPS + (t + 1)) * ISZ + (lk << 3);
                #pragma unroll
                for (int kf = 0; kf < 8; ++kf) {
                    floatx4 x0 = *(const floatx4*)(xr + (kf << 5));
                    floatx4 x1 = *(const floatx4*)(xr + (kf << 5) + 4);
                    half8 a;
                    a[0]=(_Float16)x0[0]; a[1]=(_Float16)x0[1]; a[2]=(_Float16)x0[2]; a[3]=(_Float16)x0[3];
                    a[4]=(_Float16)x1[0]; a[5]=(_Float16)x1[1]; a[6]=(_Float16)x1[2]; a[7]=(_Float16)x1[3];
                    az = __builtin_amdgcn_mfma_f32_16x16x32_f16(a, Bfrag[kf], az, 0, 0, 0);
                }
                accx = az;
            }
        }
    }
}

__global__ void out_proj(const u64* __restrict__ wsu, const unsigned* __restrict__ ctrs,
                         const float* __restrict__ Wfc, const float* __restrict__ bfc,
                         float* __restrict__ out)
{
    const int b = blockIdx.x;      // 64
    const int l = threadIdx.x;     // 64
    const bool fastm = (ctrs[9] == 1u);
    float s = 0.f;
    if (fastm) {
        const int grp = b >> 4, r = b & 15;
        const u64* mb = wsu + MIR_OFF + ((size_t)grp * 4 + 3) * 2048;  // gen 1023 slot 3
        #pragma unroll
        for (int j = 0; j < 2; ++j) {
            const int q = l + (j << 6);
            union { u64 u; half4 h; } v;
            v.u = mb[(size_t)q * 16 + r];
            #pragma unroll
            for (int e = 0; e < 4; ++e) s += (float)v.h[e] * Wfc[q * 4 + e];
        }
    } else {
        const u64* hb4 = wsu + MIR_OFF + (size_t)(T_STEPS % 3) * 8192;  // slot 1
        #pragma unroll
        for (int j = 0; j < 2; ++j) {
            const int c4 = l + (j << 6);
            union { u64 u; half4 h; } v;
            v.u = hb4[(size_t)c4 * BATCH + b];
            #pragma unroll
            for (int e = 0; e < 4; ++e) s += (float)v.h[e] * Wfc[c4 * 4 + e];
        }
    }
    #pragma unroll
    for (int off = 32; off; off >>= 1) s += __shfl_down(s, off);
    if (l == 0) out[b] = s + bfc[0];
}

extern "C" void kernel_launch(void* const* d_in, const int* in_sizes, int n_in,
                              void* d_out, int out_size, void* d_ws, size_t ws_size,
                              hipStream_t stream)
{
    const float* x   = (const float*)d_in[0];
    const float* Wf  = (const float*)d_in[1];
    const float* bf  = (const float*)d_in[2];
    const float* Wi  = (const float*)d_in[3];
    const float* bi  = (const float*)d_in[4];
    const float* Wc  = (const float*)d_in[5];
    const float* bc  = (const float*)d_in[6];
    const float* Wo  = (const float*)d_in[7];
    const float* bo  = (const float*)d_in[8];
    const float* Wfc = (const float*)d_in[9];
    const float* bfc = (const float*)d_in[10];

    u64* wsu = (u64*)d_ws;
    unsigned* ctrs   = (unsigned*)((char*)d_ws + CTR_BYTE);
    unsigned* gflags = (unsigned*)((char*)d_ws + GFL_BYTE);

    // zero team buffers, mirror, counters, flags every launch (tags 1..15;
    // zeros/poison decode as tag 0 -> never accepted)
    (void)hipMemsetAsync(d_ws, 0, WS_BYTES, stream);

    lstm_persist<<<dim3(NWG), dim3(NTHR), 0, stream>>>(
        x, Wf, bf, Wi, bi, Wc, bc, Wo, bo, wsu, ctrs, gflags);

    out_proj<<<dim3(BATCH), dim3(64), 0, stream>>>(wsu, ctrs, Wfc, bfc, (float*)d_out);
}